// Round 11
// baseline (31.134 us; speedup 1.0000x reference)
//
#include <hip/hip_runtime.h>
#include <hip/hip_bf16.h>
#include <cstdint>

// ProkBertAttention: sliding-window (+-64) attention with RoPE.
// B=4, S=2048, H=12, D=64. fp32 in/out, bf16 MFMA compute.
// Mask input (d_in[3]) ignored: band structure computed analytically.
//
// Round 11 = round 10 + OOB fix. Round-10 NaN root cause: PV's 5th kb-block
// read B-frag hi-half rows kp up to 103 (> VROWS=98) -> uninit LDS; 0*NaN=NaN.
// (Latent in rounds 6-8 too - passed on lucky garbage.) Fix: kb=4 hi half is
// not read at all (w[2]=w[3]=0; its pa is 0 anyway) -> max kp = 95, VROWS=96,
// no pad rows. Geometry unchanged: 256 thr, QT=64, 1536 blocks = 6 blocks/CU,
// two-phase shared LDS, pipelined K staging, cvt_pk, band mask kc 0/8,
// analytic OOB denominator fix, deferred norm, shared k-slot map.

typedef short bf16x8 __attribute__((ext_vector_type(8)));
typedef float f32x4  __attribute__((ext_vector_type(4)));
typedef uint32_t u32x4 __attribute__((ext_vector_type(4)));

#define SLEN   2048
#define NHEAD  12
#define NBATCH 4
#define HD     64
#define WHALF  64
#define QT     64          // queries per block (4 waves x 16)
#define KROWS  192         // QT + 2*WHALF
#define NKC    9           // per-wave key chunks (144-key span)
#define VST    68          // V-pair row stride in dwords
#define VROWS  96          // 96 key-pairs (max kp read = 95)
// scale * log2(e) = (1/8) * 1.4426950408889634 (scores in log2 units)
#define QSCALE 0.18033688011112042f

// Phase 1: sbuf holds K bf16 [192 rows][64 d] (24,576 B), 16B-chunk XOR
//          swizzle (chunk c of row rr at c ^ (rr&7)).
// Phase 2: sbuf holds V key-paired u32 [96][68] (26,112 B), cell[kp][d] =
//          (bf16 V[2kp][d], V[2kp+1][d]).
// LDS alloc = 26,112 B -> 6 blocks/CU with VGPR<=85 (launch_bounds 256,6).

__device__ __forceinline__ uint32_t cvt_pk(float lo, float hi) {
    // dst[15:0] = bf16(lo), dst[31:16] = bf16(hi); RNE (gfx950)
    uint32_t r;
    asm("v_cvt_pk_bf16_f32 %0, %1, %2" : "=v"(r) : "v"(lo), "v"(hi));
    return r;
}

__global__ __launch_bounds__(256, 6) void prokbert_attn(
        const float* __restrict__ qkv, const float* __restrict__ cosT,
        const float* __restrict__ sinT, float* __restrict__ out)
{
    __shared__ __align__(16) uint32_t sbuf[VROWS * VST];
    short* sKp = (short*)sbuf;

    const int tid = threadIdx.x;

    // ---- XCD-aware block swizzle (1536 blocks = 8 XCDs x 192, bijective) ----
    const int bid = blockIdx.x;
    const int gid = (bid & 7) * 192 + (bid >> 3);
    const int qt = gid & 31;          // 32 q-tiles per (b,h)
    const int hh = gid >> 5;          // 0..47 = b*12 + h
    const int h = hh % NHEAD, b = hh / NHEAD;

    const int q0 = qt * QT;
    const int kstart = q0 - WHALF;

    const int wv = tid >> 6;
    const int lane = tid & 63;
    const int r = lane & 15, g = lane >> 4;
    const int rx = r & 7;
    const int qrow = q0 + wv * 16 + r;

    // ======== phase 1: K staging, 3 jobs, 2-deep pipelined ========
    // job (rr, c4) owns d = c4*8..+7 AND +32; rr = rrb + it*64, it = 0,1,2.
    const int rrb = tid >> 2, c4 = tid & 3, d0 = c4 * 8;

#define LOADK(IT, S) \
    f32x4 xl0##S, xl1##S, xh0##S, xh1##S, cc0##S, cc1##S, ss0##S, ss1##S; \
    { \
        const int s = kstart + rrb + (IT) * 64; \
        if ((unsigned)s < SLEN) { \
            const size_t kbase = (((size_t)(b * SLEN + s) * 3 + 1) * NHEAD + h) * HD; \
            const f32x4* gxl = (const f32x4*)(qkv + kbase + d0); \
            const f32x4* gxh = (const f32x4*)(qkv + kbase + d0 + 32); \
            const f32x4* gc  = (const f32x4*)(cosT + s * HD + d0); \
            const f32x4* gs  = (const f32x4*)(sinT + s * HD + d0); \
            xl0##S = gxl[0]; xl1##S = gxl[1]; \
            xh0##S = gxh[0]; xh1##S = gxh[1]; \
            cc0##S = gc[0];  cc1##S = gc[1]; \
            ss0##S = gs[0];  ss1##S = gs[1]; \
        } else { \
            const f32x4 z = {0.f, 0.f, 0.f, 0.f}; \
            xl0##S = z; xl1##S = z; xh0##S = z; xh1##S = z; \
            cc0##S = z; cc1##S = z; ss0##S = z; ss1##S = z; \
        } \
    }

#define CONVSTOREK(IT, S) \
    { \
        const int rr = rrb + (IT) * 64; \
        u32x4 klo, khi; \
        /* RoPE: lo[d] = x[d]*c - x[d+32]*s ; hi[d+32] = x[d+32]*c + x[d]*s */ \
        klo[0] = cvt_pk(xl0##S[0] * cc0##S[0] - xh0##S[0] * ss0##S[0], \
                        xl0##S[1] * cc0##S[1] - xh0##S[1] * ss0##S[1]); \
        klo[1] = cvt_pk(xl0##S[2] * cc0##S[2] - xh0##S[2] * ss0##S[2], \
                        xl0##S[3] * cc0##S[3] - xh0##S[3] * ss0##S[3]); \
        klo[2] = cvt_pk(xl1##S[0] * cc1##S[0] - xh1##S[0] * ss1##S[0], \
                        xl1##S[1] * cc1##S[1] - xh1##S[1] * ss1##S[1]); \
        klo[3] = cvt_pk(xl1##S[2] * cc1##S[2] - xh1##S[2] * ss1##S[2], \
                        xl1##S[3] * cc1##S[3] - xh1##S[3] * ss1##S[3]); \
        khi[0] = cvt_pk(xh0##S[0] * cc0##S[0] + xl0##S[0] * ss0##S[0], \
                        xh0##S[1] * cc0##S[1] + xl0##S[1] * ss0##S[1]); \
        khi[1] = cvt_pk(xh0##S[2] * cc0##S[2] + xl0##S[2] * ss0##S[2], \
                        xh0##S[3] * cc0##S[3] + xl0##S[3] * ss0##S[3]); \
        khi[2] = cvt_pk(xh1##S[0] * cc1##S[0] + xl1##S[0] * ss1##S[0], \
                        xh1##S[1] * cc1##S[1] + xl1##S[1] * ss1##S[1]); \
        khi[3] = cvt_pk(xh1##S[2] * cc1##S[2] + xl1##S[2] * ss1##S[2], \
                        xh1##S[3] * cc1##S[3] + xl1##S[3] * ss1##S[3]); \
        const int sw = rr & 7; \
        *(u32x4*)&sKp[rr * 64 + ((c4 ^ sw) << 3)]       = klo; \
        *(u32x4*)&sKp[rr * 64 + (((c4 + 4) ^ sw) << 3)] = khi; \
    }

    {
        LOADK(0, a)            // issue job 0
        LOADK(1, bb)           // issue job 1 (in flight over job-0 convert)
        CONVSTOREK(0, a)       // convert+store job 0 (frees regs)
        LOADK(2, cc)           // issue job 2
        CONVSTOREK(1, bb)
        CONVSTOREK(2, cc)
    }
#undef LOADK
#undef CONVSTOREK

    // ---- Q load + RoPE + pack (after K staging: K regs dead here) ----
    bf16x8 qf0, qf1;           // k-slots: d = g*8+j and 32+g*8+j
    {
        const size_t qb = (((size_t)(b * SLEN + qrow) * 3 + 0) * NHEAD + h) * HD;
        const f32x4* ga  = (const f32x4*)(qkv + qb + g * 8);
        const f32x4* gb  = (const f32x4*)(qkv + qb + 32 + g * 8);
        const f32x4* gc0 = (const f32x4*)(cosT + (size_t)qrow * HD + g * 8);  // == cos[32+..]
        const f32x4* gs0 = (const f32x4*)(sinT + (size_t)qrow * HD + g * 8);
        f32x4 qa0 = ga[0], qa1 = ga[1], qb0 = gb[0], qb1 = gb[1];
        f32x4 qc0 = gc0[0], qc1 = gc0[1], qs0 = gs0[0], qs1 = gs0[1];
        u32x4 w0, w1;
        w0[0] = cvt_pk((qa0[0] * qc0[0] - qb0[0] * qs0[0]) * QSCALE,
                       (qa0[1] * qc0[1] - qb0[1] * qs0[1]) * QSCALE);
        w0[1] = cvt_pk((qa0[2] * qc0[2] - qb0[2] * qs0[2]) * QSCALE,
                       (qa0[3] * qc0[3] - qb0[3] * qs0[3]) * QSCALE);
        w0[2] = cvt_pk((qa1[0] * qc1[0] - qb1[0] * qs1[0]) * QSCALE,
                       (qa1[1] * qc1[1] - qb1[1] * qs1[1]) * QSCALE);
        w0[3] = cvt_pk((qa1[2] * qc1[2] - qb1[2] * qs1[2]) * QSCALE,
                       (qa1[3] * qc1[3] - qb1[3] * qs1[3]) * QSCALE);
        w1[0] = cvt_pk((qb0[0] * qc0[0] + qa0[0] * qs0[0]) * QSCALE,
                       (qb0[1] * qc0[1] + qa0[1] * qs0[1]) * QSCALE);
        w1[1] = cvt_pk((qb0[2] * qc0[2] + qa0[2] * qs0[2]) * QSCALE,
                       (qb0[3] * qc0[3] + qa0[3] * qs0[3]) * QSCALE);
        w1[2] = cvt_pk((qb1[0] * qc1[0] + qa1[0] * qs1[0]) * QSCALE,
                       (qb1[1] * qc1[1] + qa1[1] * qs1[1]) * QSCALE);
        w1[3] = cvt_pk((qb1[2] * qc1[2] + qa1[2] * qs1[2]) * QSCALE,
                       (qb1[3] * qc1[3] + qa1[3] * qs1[3]) * QSCALE);
        qf0 = __builtin_bit_cast(bf16x8, w0);
        qf1 = __builtin_bit_cast(bf16x8, w1);
    }
    __syncthreads();   // bar1: K staged

    // ===== QK^T: S^T = mfma(K_chunk, Q), lane-local; keys [wv*16, +144) =====
    f32x4 sc[NKC];
    #pragma unroll
    for (int kc = 0; kc < NKC; ++kc) {
        const int row = wv * 16 + kc * 16 + r;
        const bf16x8 ka0 = *(const bf16x8*)&sKp[row * 64 + ((g ^ rx) << 3)];
        const bf16x8 ka1 = *(const bf16x8*)&sKp[row * 64 + (((g + 4) ^ rx) << 3)];
        f32x4 c = {0.f, 0.f, 0.f, 0.f};
        c = __builtin_amdgcn_mfma_f32_16x16x32_bf16(ka0, qf0, c, 0, 0, 0);
        c = __builtin_amdgcn_mfma_f32_16x16x32_bf16(ka1, qf1, c, 0, 0, 0);
        sc[kc] = c;
    }

    // ===== softmax: exp + band mask (kc 0/8 only) + analytic OOB fix =====
    // key - qrow = kc*16 + 4g + i - r - 64: out-of-band only at kc=0 (4g+i<r)
    // and kc=8 (4g+i>r). Zero-padded K rows: score 0 -> e=1, V=0: only the
    // denominator is polluted; subtract the exact count.
    const int tg = 4 * g;
    float sum = 0.f;
    #pragma unroll
    for (int kc = 0; kc < NKC; ++kc) {
        #pragma unroll
        for (int i = 0; i < 4; ++i) {
            float e = exp2f(sc[kc][i]);   // scores already in log2 units
            if (kc == 0) e = (tg + i >= r) ? e : 0.f;
            if (kc == 8) e = (tg + i <= r) ? e : 0.f;
            sc[kc][i] = e;
            sum += e;
        }
    }
    sum += __shfl_xor(sum, 16);
    sum += __shfl_xor(sum, 32);
    const int oob = max(0, WHALF - qrow) + max(0, qrow - (SLEN - 1 - WHALF));
    const float inv = 1.f / (sum - (float)oob);

    // ---- pack PV A-frags (lane-local, unnormalized) ----
    // shared k-slot map: key(g,j) = kb*32 + (j>>2)*16 + 4g + (j&3)
    u32x4 paw[5];
    #pragma unroll
    for (int kb = 0; kb < 4; ++kb) {
        paw[kb][0] = cvt_pk(sc[2 * kb][0], sc[2 * kb][1]);
        paw[kb][1] = cvt_pk(sc[2 * kb][2], sc[2 * kb][3]);
        paw[kb][2] = cvt_pk(sc[2 * kb + 1][0], sc[2 * kb + 1][1]);
        paw[kb][3] = cvt_pk(sc[2 * kb + 1][2], sc[2 * kb + 1][3]);
    }
    paw[4][0] = cvt_pk(sc[8][0], sc[8][1]);
    paw[4][1] = cvt_pk(sc[8][2], sc[8][3]);
    paw[4][2] = 0; paw[4][3] = 0;

    // ====== phase 2: V loads (issued here; latency hides under bar2) ======
    // job j = tid + it*256: kp = j>>3 in [0,96), c8 = j&7 -> d = c8*8..+7.
    f32x4 va[3][2], vb[3][2];
    #pragma unroll
    for (int it = 0; it < 3; ++it) {
        const int j = tid + it * 256;
        const int kp = j >> 3, dd = (j & 7) * 8;
        const int s0 = kstart + 2 * kp, s1 = s0 + 1;
        const f32x4 z = {0.f, 0.f, 0.f, 0.f};
        if ((unsigned)s0 < SLEN) {
            const f32x4* g0 = (const f32x4*)(qkv +
                (((size_t)(b * SLEN + s0) * 3 + 2) * NHEAD + h) * HD + dd);
            va[it][0] = g0[0]; va[it][1] = g0[1];
        } else { va[it][0] = z; va[it][1] = z; }
        if ((unsigned)s1 < SLEN) {
            const f32x4* g1 = (const f32x4*)(qkv +
                (((size_t)(b * SLEN + s1) * 3 + 2) * NHEAD + h) * HD + dd);
            vb[it][0] = g1[0]; vb[it][1] = g1[1];
        } else { vb[it][0] = z; vb[it][1] = z; }
    }
    __syncthreads();   // bar2: all K reads done; sbuf free for V

    #pragma unroll
    for (int it = 0; it < 3; ++it) {
        const int j = tid + it * 256;
        const int kp = j >> 3, dd = (j & 7) * 8;
        u32x4 w0, w1;
        w0[0] = cvt_pk(va[it][0][0], vb[it][0][0]);
        w0[1] = cvt_pk(va[it][0][1], vb[it][0][1]);
        w0[2] = cvt_pk(va[it][0][2], vb[it][0][2]);
        w0[3] = cvt_pk(va[it][0][3], vb[it][0][3]);
        w1[0] = cvt_pk(va[it][1][0], vb[it][1][0]);
        w1[1] = cvt_pk(va[it][1][1], vb[it][1][1]);
        w1[2] = cvt_pk(va[it][1][2], vb[it][1][2]);
        w1[3] = cvt_pk(va[it][1][3], vb[it][1][3]);
        *(u32x4*)&sbuf[kp * VST + dd]     = w0;
        *(u32x4*)&sbuf[kp * VST + dd + 4] = w1;
    }
    __syncthreads();   // bar3: V staged

    // ================= O = P x V (paired-key u32 reads) =================
    // kb<4: keys kb*32 + {0,1,2,3,16,17,18,19} + 4g (pairs +0,+1,+8,+9).
    // kb=4: only lo half exists in-span; hi half pa==0 -> w[2]=w[3]=0,
    //       NO LDS read (rounds 6-10 read uninit rows here -> 0*NaN=NaN).
    const uint32_t* vptr = &sbuf[(wv * 8 + 2 * g) * VST + r];
    f32x4 oacc[4] = {{0,0,0,0},{0,0,0,0},{0,0,0,0},{0,0,0,0}};
    #pragma unroll
    for (int kb = 0; kb < 5; ++kb) {
        const bf16x8 pa = __builtin_bit_cast(bf16x8, paw[kb]);
        #pragma unroll
        for (int dc = 0; dc < 4; ++dc) {
            const int base = kb * 16 * VST + dc * 16;
            u32x4 w;
            w[0] = vptr[base];                 // keys kb*32+4g, +1
            w[1] = vptr[base + VST];           // +2, +3
            if (kb < 4) {
                w[2] = vptr[base + 8 * VST];   // +16, +17
                w[3] = vptr[base + 9 * VST];   // +18, +19
            } else {
                w[2] = 0; w[3] = 0;            // pa hi == 0; avoid OOB read
            }
            const bf16x8 vbf = __builtin_bit_cast(bf16x8, w);
            oacc[dc] = __builtin_amdgcn_mfma_f32_16x16x32_bf16(pa, vbf, oacc[dc], 0, 0, 0);
        }
    }

    // ---- store (C row = query = g*4+i, col = d = r), deferred norm ----
    #pragma unroll
    for (int i = 0; i < 4; ++i) {
        const float iq = __shfl(inv, g * 4 + i);   // inv depends only on lane&15
        const int qg = q0 + wv * 16 + g * 4 + i;
        float* orow = out + (((size_t)(b * SLEN + qg)) * NHEAD + h) * HD + r;
        orow[0]  = oacc[0][i] * iq;
        orow[16] = oacc[1][i] * iq;
        orow[32] = oacc[2][i] * iq;
        orow[48] = oacc[3][i] * iq;
    }
}

extern "C" void kernel_launch(void* const* d_in, const int* in_sizes, int n_in,
                              void* d_out, int out_size, void* d_ws, size_t ws_size,
                              hipStream_t stream) {
    const float* qkv  = (const float*)d_in[0];
    const float* cosT = (const float*)d_in[1];
    const float* sinT = (const float*)d_in[2];
    // d_in[3] = mask: unused (band structure computed analytically)
    float* out = (float*)d_out;
    dim3 grid(32 * NHEAD * NBATCH);   // 1536 = 6 blocks/CU x 256 CUs, no tail
    dim3 block(256);
    hipLaunchKernelGGL(prokbert_attn, grid, block, 0, stream, qkv, cosT, sinT, out);
}

// Round 12
// 27.196 us; speedup vs baseline: 1.1448x; 1.1448x over previous
//
#include <hip/hip_runtime.h>
#include <hip/hip_bf16.h>
#include <cstdint>

// ProkBertAttention: sliding-window (+-64) attention with RoPE.
// B=4, S=2048, H=12, D=64. fp32 in/out, bf16 MFMA compute.
// Mask input (d_in[3]) ignored: band structure computed analytically.
//
// Round 12 (base = round 9, 27.3us): (a) K LDS stride 144B, XOR removed --
// r11 counters traced 1.47M bank-conflict cycles to K *writes* (row stride
// 128B = 32 banks: write quad (rr+c4)%8 hit 4-8x); stride 144B gives read
// quad 9r+g (2x=free) and write ~2-3-way. (b) fused QK->mask->exp->pack
// (deferred norm means P needs no sum first): sc[9] (36 VGPR) eliminated.
// (c) V rows = 128 exactly, no pad/zero-fill (kb=4 reads lo half only,
// r11 fix). Geometry (512thr, QT=128, 768 blocks = 3/CU, two-phase LDS,
// pipelined K staging, Q-after-K, analytic OOB, XCD swizzle) unchanged.
// Known-bad configs: (256,6) mis-compiles (VGPR=40 + spills, r8/r11).

typedef short bf16x8 __attribute__((ext_vector_type(8)));
typedef float f32x4  __attribute__((ext_vector_type(4)));
typedef uint32_t u32x4 __attribute__((ext_vector_type(4)));

#define SLEN   2048
#define NHEAD  12
#define NBATCH 4
#define HD     64
#define WHALF  64
#define QT     128         // queries per block (8 waves x 16)
#define KROWS  256         // QT + 2*WHALF
#define NKC    9           // per-wave key chunks (144-key span)
#define KSTR   72          // K row stride in shorts (144B: quad 9r+g, 2-way)
#define VST    68          // V-pair row stride in dwords
#define VROWS  128         // key-pairs (max kp read = 127, exact)
// scale * log2(e) = (1/8) * 1.4426950408889634 (scores in log2 units)
#define QSCALE 0.18033688011112042f

// Phase 1: sbuf holds K bf16 [256 rows][72 stride] (36,864 B), plain layout.
// Phase 2: sbuf holds V key-paired u32 [128][68] (34,816 B), cell[kp][d] =
//          (bf16 V[2kp][d], V[2kp+1][d]).
// LDS alloc = 36,864 B -> 3 blocks/CU (24 waves) with launch_bounds(512,6).

__device__ __forceinline__ uint32_t cvt_pk(float lo, float hi) {
    // dst[15:0] = bf16(lo), dst[31:16] = bf16(hi); RNE (gfx950)
    uint32_t r;
    asm("v_cvt_pk_bf16_f32 %0, %1, %2" : "=v"(r) : "v"(lo), "v"(hi));
    return r;
}

__global__ __launch_bounds__(512, 6) void prokbert_attn(
        const float* __restrict__ qkv, const float* __restrict__ cosT,
        const float* __restrict__ sinT, float* __restrict__ out)
{
    __shared__ __align__(16) uint32_t sbuf[KROWS * KSTR / 2];   // 9216 dwords
    short* sKp = (short*)sbuf;

    const int tid = threadIdx.x;

    // ---- XCD-aware block swizzle (768 blocks = 8 XCDs x 96, bijective) ----
    const int bid = blockIdx.x;
    const int gid = (bid & 7) * 96 + (bid >> 3);
    const int qt = gid & 15;
    const int hh = gid >> 4;          // 0..47 = b*12 + h
    const int h = hh % NHEAD, b = hh / NHEAD;

    const int q0 = qt * QT;
    const int kstart = q0 - WHALF;

    const int wv = tid >> 6;
    const int lane = tid & 63;
    const int r = lane & 15, g = lane >> 4;
    const int qrow = q0 + wv * 16 + r;

    // ================= phase 1: K staging, 2-deep pipelined =================
    // job (rr, c4) owns d = c4*8..+7 AND +32; rr = rrb + it*128, it = 0,1.
    const int rrb = tid >> 2, c4 = tid & 3, d0 = c4 * 8;

#define LOADK(IT, S) \
    f32x4 xl0##S, xl1##S, xh0##S, xh1##S, cc0##S, cc1##S, ss0##S, ss1##S; \
    { \
        const int s = kstart + rrb + (IT) * 128; \
        if ((unsigned)s < SLEN) { \
            const size_t kbase = (((size_t)(b * SLEN + s) * 3 + 1) * NHEAD + h) * HD; \
            const f32x4* gxl = (const f32x4*)(qkv + kbase + d0); \
            const f32x4* gxh = (const f32x4*)(qkv + kbase + d0 + 32); \
            const f32x4* gc  = (const f32x4*)(cosT + s * HD + d0); \
            const f32x4* gs  = (const f32x4*)(sinT + s * HD + d0); \
            xl0##S = gxl[0]; xl1##S = gxl[1]; \
            xh0##S = gxh[0]; xh1##S = gxh[1]; \
            cc0##S = gc[0];  cc1##S = gc[1]; \
            ss0##S = gs[0];  ss1##S = gs[1]; \
        } else { \
            const f32x4 z = {0.f, 0.f, 0.f, 0.f}; \
            xl0##S = z; xl1##S = z; xh0##S = z; xh1##S = z; \
            cc0##S = z; cc1##S = z; ss0##S = z; ss1##S = z; \
        } \
    }

#define CONVSTOREK(IT, S) \
    { \
        const int rr = rrb + (IT) * 128; \
        u32x4 klo, khi; \
        /* RoPE: lo[d] = x[d]*c - x[d+32]*s ; hi[d+32] = x[d+32]*c + x[d]*s */ \
        klo[0] = cvt_pk(xl0##S[0] * cc0##S[0] - xh0##S[0] * ss0##S[0], \
                        xl0##S[1] * cc0##S[1] - xh0##S[1] * ss0##S[1]); \
        klo[1] = cvt_pk(xl0##S[2] * cc0##S[2] - xh0##S[2] * ss0##S[2], \
                        xl0##S[3] * cc0##S[3] - xh0##S[3] * ss0##S[3]); \
        klo[2] = cvt_pk(xl1##S[0] * cc1##S[0] - xh1##S[0] * ss1##S[0], \
                        xl1##S[1] * cc1##S[1] - xh1##S[1] * ss1##S[1]); \
        klo[3] = cvt_pk(xl1##S[2] * cc1##S[2] - xh1##S[2] * ss1##S[2], \
                        xl1##S[3] * cc1##S[3] - xh1##S[3] * ss1##S[3]); \
        khi[0] = cvt_pk(xh0##S[0] * cc0##S[0] + xl0##S[0] * ss0##S[0], \
                        xh0##S[1] * cc0##S[1] + xl0##S[1] * ss0##S[1]); \
        khi[1] = cvt_pk(xh0##S[2] * cc0##S[2] + xl0##S[2] * ss0##S[2], \
                        xh0##S[3] * cc0##S[3] + xl0##S[3] * ss0##S[3]); \
        khi[2] = cvt_pk(xh1##S[0] * cc1##S[0] + xl1##S[0] * ss1##S[0], \
                        xh1##S[1] * cc1##S[1] + xl1##S[1] * ss1##S[1]); \
        khi[3] = cvt_pk(xh1##S[2] * cc1##S[2] + xl1##S[2] * ss1##S[2], \
                        xh1##S[3] * cc1##S[3] + xl1##S[3] * ss1##S[3]); \
        *(u32x4*)&sKp[rr * KSTR + d0]      = klo; \
        *(u32x4*)&sKp[rr * KSTR + 32 + d0] = khi; \
    }

    {
        LOADK(0, a)            // issue batch 0
        LOADK(1, bb)           // issue batch 1 (in flight over batch-0 convert)
        CONVSTOREK(0, a)       // convert+store batch 0 (frees regs)
        CONVSTOREK(1, bb)
    }
#undef LOADK
#undef CONVSTOREK

    // ---- Q load + RoPE + pack (after K staging: K regs dead here) ----
    bf16x8 qf0, qf1;           // k-slots: d = g*8+j and 32+g*8+j
    {
        const size_t qb = (((size_t)(b * SLEN + qrow) * 3 + 0) * NHEAD + h) * HD;
        const f32x4* ga  = (const f32x4*)(qkv + qb + g * 8);
        const f32x4* gb  = (const f32x4*)(qkv + qb + 32 + g * 8);
        const f32x4* gc0 = (const f32x4*)(cosT + (size_t)qrow * HD + g * 8);  // == cos[32+..]
        const f32x4* gs0 = (const f32x4*)(sinT + (size_t)qrow * HD + g * 8);
        f32x4 qa0 = ga[0], qa1 = ga[1], qb0 = gb[0], qb1 = gb[1];
        f32x4 qc0 = gc0[0], qc1 = gc0[1], qs0 = gs0[0], qs1 = gs0[1];
        u32x4 w0, w1;
        w0[0] = cvt_pk((qa0[0] * qc0[0] - qb0[0] * qs0[0]) * QSCALE,
                       (qa0[1] * qc0[1] - qb0[1] * qs0[1]) * QSCALE);
        w0[1] = cvt_pk((qa0[2] * qc0[2] - qb0[2] * qs0[2]) * QSCALE,
                       (qa0[3] * qc0[3] - qb0[3] * qs0[3]) * QSCALE);
        w0[2] = cvt_pk((qa1[0] * qc1[0] - qb1[0] * qs1[0]) * QSCALE,
                       (qa1[1] * qc1[1] - qb1[1] * qs1[1]) * QSCALE);
        w0[3] = cvt_pk((qa1[2] * qc1[2] - qb1[2] * qs1[2]) * QSCALE,
                       (qa1[3] * qc1[3] - qb1[3] * qs1[3]) * QSCALE);
        w1[0] = cvt_pk((qb0[0] * qc0[0] + qa0[0] * qs0[0]) * QSCALE,
                       (qb0[1] * qc0[1] + qa0[1] * qs0[1]) * QSCALE);
        w1[1] = cvt_pk((qb0[2] * qc0[2] + qa0[2] * qs0[2]) * QSCALE,
                       (qb0[3] * qc0[3] + qa0[3] * qs0[3]) * QSCALE);
        w1[2] = cvt_pk((qb1[0] * qc1[0] + qa1[0] * qs1[0]) * QSCALE,
                       (qb1[1] * qc1[1] + qa1[1] * qs1[1]) * QSCALE);
        w1[3] = cvt_pk((qb1[2] * qc1[2] + qa1[2] * qs1[2]) * QSCALE,
                       (qb1[3] * qc1[3] + qa1[3] * qs1[3]) * QSCALE);
        qf0 = __builtin_bit_cast(bf16x8, w0);
        qf1 = __builtin_bit_cast(bf16x8, w1);
    }
    __syncthreads();   // bar1: K staged

    // ===== fused QK^T -> mask -> exp -> P-pack (deferred norm: no sum pass) =====
    // S^T = mfma(K_chunk, Q): C row = key-in-chunk = 4g+i, C col = query = r.
    // Band mask only at kc=0 (4g+i<r) and kc=8 (4g+i>r); OOB rows give score
    // 0 -> e=1, V=0: denominator fixed analytically below.
    // paw k-slot map: key(g,j) = kb*32 + (j>>2)*16 + 4g + (j&3).
    u32x4 paw[5];
    float sum = 0.f;
    const int tg = 4 * g;
    #pragma unroll
    for (int kc = 0; kc < NKC; ++kc) {
        const int row = wv * 16 + kc * 16 + r;
        const bf16x8 ka0 = *(const bf16x8*)&sKp[row * KSTR + g * 8];
        const bf16x8 ka1 = *(const bf16x8*)&sKp[row * KSTR + 32 + g * 8];
        f32x4 c = {0.f, 0.f, 0.f, 0.f};
        c = __builtin_amdgcn_mfma_f32_16x16x32_bf16(ka0, qf0, c, 0, 0, 0);
        c = __builtin_amdgcn_mfma_f32_16x16x32_bf16(ka1, qf1, c, 0, 0, 0);
        f32x4 e;
        #pragma unroll
        for (int i = 0; i < 4; ++i) {
            float ev = exp2f(c[i]);   // scores already in log2 units
            if (kc == 0) ev = (tg + i >= r) ? ev : 0.f;
            if (kc == 8) ev = (tg + i <= r) ? ev : 0.f;
            e[i] = ev;
            sum += ev;
        }
        const uint32_t wlo = cvt_pk(e[0], e[1]);
        const uint32_t whi = cvt_pk(e[2], e[3]);
        if ((kc & 1) == 0) { paw[kc >> 1][0] = wlo; paw[kc >> 1][1] = whi; }
        else               { paw[kc >> 1][2] = wlo; paw[kc >> 1][3] = whi; }
    }
    paw[4][2] = 0; paw[4][3] = 0;

    sum += __shfl_xor(sum, 16);
    sum += __shfl_xor(sum, 32);
    const int oob = max(0, WHALF - qrow) + max(0, qrow - (SLEN - 1 - WHALF));
    const float inv = 1.f / (sum - (float)oob);

    // ================= phase 2: V loads (latency hides under bar2) =========
    const int vkp = tid >> 2, vdb = tid & 3, vd0 = vdb * 16;
    const int s0 = kstart + 2 * vkp, s1 = s0 + 1;
    f32x4 va[4], vb4[4];
    {
        const f32x4 z = {0.f, 0.f, 0.f, 0.f};
        if ((unsigned)s0 < SLEN) {
            const f32x4* g0 = (const f32x4*)(qkv +
                (((size_t)(b * SLEN + s0) * 3 + 2) * NHEAD + h) * HD + vd0);
            va[0] = g0[0]; va[1] = g0[1]; va[2] = g0[2]; va[3] = g0[3];
        } else { va[0] = z; va[1] = z; va[2] = z; va[3] = z; }
        if ((unsigned)s1 < SLEN) {
            const f32x4* g1 = (const f32x4*)(qkv +
                (((size_t)(b * SLEN + s1) * 3 + 2) * NHEAD + h) * HD + vd0);
            vb4[0] = g1[0]; vb4[1] = g1[1]; vb4[2] = g1[2]; vb4[3] = g1[3];
        } else { vb4[0] = z; vb4[1] = z; vb4[2] = z; vb4[3] = z; }
    }
    __syncthreads();   // bar2: all K reads done; sbuf free for V

    #pragma unroll
    for (int u = 0; u < 4; ++u) {
        u32x4 dw;
        dw[0] = cvt_pk(va[u][0], vb4[u][0]);
        dw[1] = cvt_pk(va[u][1], vb4[u][1]);
        dw[2] = cvt_pk(va[u][2], vb4[u][2]);
        dw[3] = cvt_pk(va[u][3], vb4[u][3]);
        *(u32x4*)&sbuf[vkp * VST + vd0 + u * 4] = dw;
    }
    __syncthreads();   // bar3: V staged

    // ================= O = P x V (paired-key u32 reads) =================
    // kb<4: keys kb*32 + {0,1,2,3,16,17,18,19} + 4g (pairs +0,+1,+8,+9).
    // kb=4: lo half only (hi pa==0 -> w[2]=w[3]=0, no LDS read; max kp=127).
    const uint32_t* vptr = &sbuf[(wv * 8 + 2 * g) * VST + r];
    f32x4 oacc[4] = {{0,0,0,0},{0,0,0,0},{0,0,0,0},{0,0,0,0}};
    #pragma unroll
    for (int kb = 0; kb < 5; ++kb) {
        const bf16x8 pa = __builtin_bit_cast(bf16x8, paw[kb]);
        #pragma unroll
        for (int dc = 0; dc < 4; ++dc) {
            const int base = kb * 16 * VST + dc * 16;
            u32x4 w;
            w[0] = vptr[base];                 // keys kb*32+4g, +1
            w[1] = vptr[base + VST];           // +2, +3
            if (kb < 4) {
                w[2] = vptr[base + 8 * VST];   // +16, +17
                w[3] = vptr[base + 9 * VST];   // +18, +19
            } else {
                w[2] = 0; w[3] = 0;            // pa hi == 0; avoid OOB read
            }
            const bf16x8 vb = __builtin_bit_cast(bf16x8, w);
            oacc[dc] = __builtin_amdgcn_mfma_f32_16x16x32_bf16(pa, vb, oacc[dc], 0, 0, 0);
        }
    }

    // ---- store (C row = query = g*4+i, col = d = r), deferred norm ----
    #pragma unroll
    for (int i = 0; i < 4; ++i) {
        const float iq = __shfl(inv, g * 4 + i);   // inv depends only on lane&15
        const int qg = q0 + wv * 16 + g * 4 + i;
        float* orow = out + (((size_t)(b * SLEN + qg)) * NHEAD + h) * HD + r;
        orow[0]  = oacc[0][i] * iq;
        orow[16] = oacc[1][i] * iq;
        orow[32] = oacc[2][i] * iq;
        orow[48] = oacc[3][i] * iq;
    }
}

extern "C" void kernel_launch(void* const* d_in, const int* in_sizes, int n_in,
                              void* d_out, int out_size, void* d_ws, size_t ws_size,
                              hipStream_t stream) {
    const float* qkv  = (const float*)d_in[0];
    const float* cosT = (const float*)d_in[1];
    const float* sinT = (const float*)d_in[2];
    // d_in[3] = mask: unused (band structure computed analytically)
    float* out = (float*)d_out;
    dim3 grid(16 * NHEAD * NBATCH);   // 768 = 3 blocks/CU x 256 CUs, no tail
    dim3 block(512);
    hipLaunchKernelGGL(prokbert_attn, grid, block, 0, stream, qkv, cosT, sinT, out);
}